// Round 9
// baseline (440.458 us; speedup 1.0000x reference)
//
#include <hip/hip_runtime.h>
#include <hip/hip_bf16.h>

// AngularMarginLoss: B=2048, D=256, C=100000
// loss = -mean_b( num_b - log(exp(num_b) + sum_{c!=t_b} exp(30*cos_bc) + 1e-6) )
// num_b = 30*cos(acos(clip(cos_bt)) + 0.2)
//
// Round-16: R15's serial-sum check (LDS 61 + MFMA 50 + VALU 42 ~= 161
// measured) proved NO pipe overlap at ~1 wave/SIMD residency; R10's "LDS
// bound" 132us was partial overlap of a larger sum at 6 waves/CU. Objective:
// minimize per-wave SERIAL cycles, keep VGPR low enough for 2 waves/SIMD.
//  * A entirely in REGISTERS: wave owns 64 classes, afrag[4][8]=128 VGPR.
//    Zero per-MFMA A-reads (R10/R15 paid 16B/lane LDS per 1-2 MFMAs).
//  * B staged in LDS once per block, shared by 2 waves: Mc=128 -> B-global
//    halves to 0.8GB; 1 ds_read_b128 feeds 4 MFMAs (4B/lane/MFMA = 31us/CU,
//    the only per-MFMA memory cost left).
//  * Sample-split 2: block = (slice of 128 classes) x (1024 samples); grid
//    1564 (6.1 blocks/CU, 87% balance); partial stays [1564][2048] (row =
//    sl*2+wv) so k_finish is byte-identical. W read 2x (=200MB HBM, cheap).
//  * Staging = reg-relay (T14): issue 8 global loads -> compute supertile ->
//    ds_write -> barrier (33 barriers total). Avoids global_load_lds
//    compile risk; loads hide under the ~1000-cyc compute phase.
//  * __launch_bounds__(128,1): empirical caps are 256/arg2 (R11/R12/R14/R15)
//    -> arg2=1 keeps the full 256 budget so afrag stays in regs.
//  * embF pre-scaled by 30*log2(e): exp(30*cos) = one v_exp2_f32.

static constexpr int Bn = 2048;
static constexpr int Dn = 256;
static constexpr int Cn = 100000;
static constexpr int MC = 128;                      // classes per block
static constexpr int NSL = 782;                     // class slices (128 wide)
static constexpr int CPAD   = NSL * MC;             // 100096
static constexpr float OOB_COLS = (float)(CPAD - Cn);   // 96 (exp2(0)=1 each)
static constexpr int NROWS = NSL * 2;               // 1564 partial rows
static constexpr int NST = 32;                      // supertiles (32 samp) / block

#define SCALE_F 30.0f
#define MARGIN_F 0.2f
#define EPS_F 1e-6f
#define L2E_SCALE 43.2808512266689f   /* 30 * log2(e): exp(30*c) = 2^(L2E*c) */

typedef __attribute__((ext_vector_type(8))) short bf16x8;   // 8 bf16 = 4 VGPRs
typedef __attribute__((ext_vector_type(4))) float f32x4;

__device__ __forceinline__ short f2bf_rne(float x) {
    union { float f; unsigned int u; } v; v.f = x;
    unsigned int r = v.u + 0x7fffu + ((v.u >> 16) & 1u);
    return (short)(r >> 16);
}

// ---- kernel 1: fused prep ----
// blocks [0,256)    : pack emb fp32 -> embF (bf16, 16x16x32 MFMA B-fragment
//                     order, 16-wide tiles), PRE-SCALED by 30*log2(e).
//   chunk (t,ks,lane): embF[((t*8+ks)*64+lane)*8 .. +7] = bf16 of
//   L2E * emb[t*16 + (lane&15)][ks*32 + (lane>>4)*8 + j], j=0..7
// blocks [256,768)  : per-sample target cosine -> numv, etv (exact fp32 path)
__global__ __launch_bounds__(256) void k_prep(const float* __restrict__ W,
                                              const float* __restrict__ emb,
                                              const int* __restrict__ tgt,
                                              short* __restrict__ embF,
                                              float* __restrict__ numv,
                                              float* __restrict__ etv) {
    const int blk = blockIdx.x;
    if (blk < 256) {
        const int t     = blk >> 1;
        const int chunk = (blk & 1) * 256 + threadIdx.x;   // [0,512)
        const int ks    = chunk >> 6;
        const int lane  = chunk & 63;
        const int q     = lane >> 4;
        const int cr    = lane & 15;
        const float* src = emb + (size_t)(t * 16 + cr) * Dn + ks * 32 + q * 8;
        float4 x0 = *(const float4*)(src);
        float4 x1 = *(const float4*)(src + 4);
        bf16x8 o;
        o[0] = f2bf_rne(x0.x * L2E_SCALE); o[1] = f2bf_rne(x0.y * L2E_SCALE);
        o[2] = f2bf_rne(x0.z * L2E_SCALE); o[3] = f2bf_rne(x0.w * L2E_SCALE);
        o[4] = f2bf_rne(x1.x * L2E_SCALE); o[5] = f2bf_rne(x1.y * L2E_SCALE);
        o[6] = f2bf_rne(x1.z * L2E_SCALE); o[7] = f2bf_rne(x1.w * L2E_SCALE);
        *(bf16x8*)(embF + (size_t)((t * 8 + ks) * 64 + lane) * 8) = o;
    } else {
        const int b    = (blk - 256) * 4 + (threadIdx.x >> 6);
        const int lane = threadIdx.x & 63;
        const int t    = tgt[b];
        float4 x = *(const float4*)(W + (size_t)t * Dn + lane * 4);
        float4 e = *(const float4*)(emb + b * Dn + lane * 4);
        float dot = x.x * e.x + x.y * e.y + x.z * e.z + x.w * e.w;
        float ss  = x.x * x.x + x.y * x.y + x.z * x.z + x.w * x.w;
#pragma unroll
        for (int o = 1; o < 64; o <<= 1) {
            dot += __shfl_xor(dot, o);
            ss  += __shfl_xor(ss, o);
        }
        if (lane == 0) {
            float cosv = dot / fmaxf(sqrtf(ss), 1e-12f);
            cosv = fminf(fmaxf(cosv, -1.f), 1.f);
            const float num = SCALE_F * cosf(acosf(cosv) + MARGIN_F);
            numv[b] = num;
            etv[b]  = __expf(SCALE_F * cosv);
        }
    }
}

// ---- kernel 2: main fused GEMM + exp row-sum ----
// Block (sl, half): 128 classes x 1024 samples, 2 waves (128 thr). Wave wv
// owns classes [sl*128 + wv*64, +64) with A-fragments IN REGISTERS; B
// supertiles (32 samples, 16KB) double-buffered in LDS, shared by both waves.
__global__ __launch_bounds__(128, 1) void k_main(const float* __restrict__ W,
                                                 const short* __restrict__ embF,
                                                 float* __restrict__ partial) {
    __shared__ short buf[2][8192];   // 2 x 16KB supertile buffers
    const int tid  = threadIdx.x;
    const int lane = tid & 63;
    const int wv   = tid >> 6;       // wave 0..1
    const int q    = lane >> 4;      // quad 0..3
    const int cr   = lane & 15;
    const int sl   = blockIdx.x >> 1;
    const int half = blockIdx.x & 1;
    const int cbase = sl * MC + wv * 64;

    // B source for this sample-half (16-tile t occupies 8KB, contiguous)
    const char* bsrc = (const char*)embF + (size_t)(half * 64) * 8192;

    // issue stage-0 loads FIRST: they fly while the prologue streams W
    float4 r[8];
    {
        const char* src = bsrc + wv * 8192;
#pragma unroll
        for (int j = 0; j < 8; ++j)
            r[j] = *(const float4*)(src + j * 1024 + lane * 16);
    }

    // ---- prologue: this wave normalizes ITS 64 classes into afrag REGS ----
    // A layout (16x16x32): lane holds A[m=cr][k=q*8+j] per 32-wide k-step.
    bf16x8 afrag[4][8];
#pragma unroll
    for (int ct = 0; ct < 4; ++ct) {
        const int c = cbase + ct * 16 + cr;
        const float* wr = W + (size_t)c * Dn;
        float ss = 0.0f;
        if (c < Cn) {
#pragma unroll
            for (int ks = 0; ks < 8; ++ks) {
                float4 x0 = *(const float4*)(wr + ks * 32 + q * 8);
                float4 x1 = *(const float4*)(wr + ks * 32 + q * 8 + 4);
                ss += x0.x * x0.x + x0.y * x0.y + x0.z * x0.z + x0.w * x0.w;
                ss += x1.x * x1.x + x1.y * x1.y + x1.z * x1.z + x1.w * x1.w;
            }
        }
        // lanes {cr, cr+16, cr+32, cr+48} hold 64 distinct elements of row c
        ss += __shfl_xor(ss, 16);
        ss += __shfl_xor(ss, 32);
        const float rn = 1.0f / fmaxf(sqrtf(ss), 1e-12f);
#pragma unroll
        for (int ks = 0; ks < 8; ++ks) {
            bf16x8 a = {0, 0, 0, 0, 0, 0, 0, 0};
            if (c < Cn) {   // pass 2: reload (cache-hot), scale, convert
                float4 x0 = *(const float4*)(wr + ks * 32 + q * 8);
                float4 x1 = *(const float4*)(wr + ks * 32 + q * 8 + 4);
                a[0] = f2bf_rne(x0.x * rn); a[1] = f2bf_rne(x0.y * rn);
                a[2] = f2bf_rne(x0.z * rn); a[3] = f2bf_rne(x0.w * rn);
                a[4] = f2bf_rne(x1.x * rn); a[5] = f2bf_rne(x1.y * rn);
                a[6] = f2bf_rne(x1.z * rn); a[7] = f2bf_rne(x1.w * rn);
            }
            afrag[ct][ks] = a;
        }
    }

    // write stage-0, publish
    {
        char* dst = (char*)&buf[0][0] + wv * 8192;
#pragma unroll
        for (int j = 0; j < 8; ++j)
            *(float4*)(dst + j * 1024 + lane * 16) = r[j];
    }
    __syncthreads();

    float* rowp = partial + (size_t)(sl * 2 + wv) * Bn + half * 1024;

    int cur = 0;
    for (int st = 0; st < NST; ++st) {
        // issue next-supertile loads (hide HBM/L2 latency under compute)
        if (st + 1 < NST) {
            const char* src = bsrc + (size_t)(st + 1) * 16384 + wv * 8192;
#pragma unroll
            for (int j = 0; j < 8; ++j)
                r[j] = *(const float4*)(src + j * 1024 + lane * 16);
        }
        // compute the supertile's two 16-tiles; A from regs, B from LDS
#pragma unroll
        for (int h = 0; h < 2; ++h) {
            const short* bb = &buf[cur][h * 4096];
            f32x4 a0 = {0.f, 0.f, 0.f, 0.f};
            f32x4 a1 = a0, a2 = a0, a3 = a0;
#pragma unroll
            for (int ks = 0; ks < 8; ++ks) {
                bf16x8 bf = *(const bf16x8*)(bb + (size_t)(ks * 64 + lane) * 8);
                a0 = __builtin_amdgcn_mfma_f32_16x16x32_bf16(afrag[0][ks], bf, a0, 0, 0, 0);
                a1 = __builtin_amdgcn_mfma_f32_16x16x32_bf16(afrag[1][ks], bf, a1, 0, 0, 0);
                a2 = __builtin_amdgcn_mfma_f32_16x16x32_bf16(afrag[2][ks], bf, a2, 0, 0, 0);
                a3 = __builtin_amdgcn_mfma_f32_16x16x32_bf16(afrag[3][ks], bf, a3, 0, 0, 0);
            }
            // D: col=lane&15=sample, row=q*4+reg=class. d=30*log2e*cos -> exp2.
            float s0 = 0.f, s1 = 0.f, s2 = 0.f, s3 = 0.f;
#pragma unroll
            for (int rr = 0; rr < 4; ++rr) {
                s0 += __builtin_amdgcn_exp2f(a0[rr]);
                s1 += __builtin_amdgcn_exp2f(a1[rr]);
                s2 += __builtin_amdgcn_exp2f(a2[rr]);
                s3 += __builtin_amdgcn_exp2f(a3[rr]);
            }
            float s = (s0 + s1) + (s2 + s3);
            s += __shfl_xor(s, 16);      // fold q: every lane gets the full
            s += __shfl_xor(s, 32);      // 64-class sum for its cr
            if (lane < 16) rowp[(st * 2 + h) * 16 + cr] = s;   // 64B store
        }
        // land staged regs into the other buffer, then publish
        if (st + 1 < NST) {
            char* dst = (char*)&buf[cur ^ 1][0] + wv * 8192;
#pragma unroll
            for (int j = 0; j < 8; ++j)
                *(float4*)(dst + j * 1024 + lane * 16) = r[j];
        }
        __syncthreads();
        cur ^= 1;
    }
}

// ---- kernel 3: fused rowsum + loss ----
// 128 blocks x 256 thr; block owns 16 samples; tid = chunk*16 + l.
__global__ __launch_bounds__(256) void k_finish(const float* __restrict__ partial,
                                                const float* __restrict__ numv,
                                                const float* __restrict__ etv,
                                                float* __restrict__ out) {
    __shared__ float red[16];
    const int l     = threadIdx.x & 15;          // sample within block
    const int chunk = threadIdx.x >> 4;          // 0..15
    const int b  = blockIdx.x * 16 + l;

    if (threadIdx.x < 16) red[threadIdx.x] = 0.0f;
    __syncthreads();

    float acc = 0.0f;
    for (int s = chunk; s < NROWS; s += 16) acc += partial[(size_t)s * Bn + b];
    // wave holds 4 chunks x 16 samples: fold chunks in-wave first
    acc += __shfl_xor(acc, 16);
    acc += __shfl_xor(acc, 32);
    if ((threadIdx.x & 63) < 16) atomicAdd(&red[l], acc);
    __syncthreads();

    if (threadIdx.x < 16) {
        const int bb = blockIdx.x * 16 + threadIdx.x;
        const float num  = numv[bb];
        const float excl = red[threadIdx.x] - OOB_COLS - etv[bb];  // drop pad + target
        float term = num - logf(__expf(num) + excl + EPS_F);
#pragma unroll
        for (int o = 1; o < 16; o <<= 1) term += __shfl_xor(term, o);
        if (threadIdx.x == 0) atomicAdd(out, -term / (float)Bn);
    }
}

extern "C" void kernel_launch(void* const* d_in, const int* in_sizes, int n_in,
                              void* d_out, int out_size, void* d_ws, size_t ws_size,
                              hipStream_t stream) {
    const float* emb = (const float*)d_in[0];   // 2048*256
    const float* W   = (const float*)d_in[1];   // 100000*256
    const int*   tgt = (const int*)d_in[2];     // 2048
    float* out = (float*)d_out;

    char* ws = (char*)d_ws;
    short* embF    = (short*)ws;                             // 1 MB (fragment order)
    float* partial = (float*)(ws + (1 << 20));               // 1564*2048*4 = 12.8 MB
    float* numv    = partial + (size_t)NROWS * Bn;           // 8 KB
    float* etv     = numv + Bn;                              // 8 KB

    hipMemsetAsync(out, 0, sizeof(float), stream);
    k_prep<<<768, 256, 0, stream>>>(W, emb, tgt, embF, numv, etv);
    k_main<<<NROWS, 128, 0, stream>>>(W, embF, partial);
    k_finish<<<128, 256, 0, stream>>>(partial, numv, etv, out);
}

// Round 10
// 259.455 us; speedup vs baseline: 1.6976x; 1.6976x over previous
//
#include <hip/hip_runtime.h>
#include <hip/hip_bf16.h>

// AngularMarginLoss: B=2048, D=256, C=100000
// loss = -mean_b( num_b - log(exp(num_b) + sum_{c!=t_b} exp(30*cos_bc) + 1e-6) )
// num_b = 30*cos(acos(clip(cos_bt)) + 0.2)
//
// Round-17: REVERT to the round-2 champion (k_main 132us, total 258.8us --
// best of 9 measured configs) + exactly ONE additive tweak:
//  * T5 s_setprio(1)/(0) around the MFMA cluster. R10's main loop is
//    barrier-free, so waves drift into different phases (load/MFMA/exp) --
//    the independent-wave regime where setprio measured +4-7% (attn m191)
//    and only nulls in lockstep schedules (m190). MFMA-entering waves get
//    CU-scheduler preference over waves in their exp/store tail.
// Rationale: 7 structural rewrites (R11-R16: bigger blocks, 32x32, Mc=128,
// A-in-regs, LDS staging) all lost to this config -- its memory plumbing
// (A from LDS 1 read/MFMA, B direct-from-global ping-pong hitting L2/L3) is
// a verified local optimum at ~65% combined MFMA+VALU busy.
//  * 4 waves/block, one 64-class slice; waves cooperatively normalize W
//    (16 cols each, 1x traffic), share bf16 A-fragments via 32KB LDS, then
//    run 32 sample-tiles each with NO further barriers.
//  * embF pre-scaled by 30*log2(e): exp(30*cos) = one v_exp2_f32.
//  * Coalesced 64B partial stores; k_finish does the cross-slice rowsum.

static constexpr int Bn = 2048;
static constexpr int Dn = 256;
static constexpr int Cn = 100000;
static constexpr int NSLICE = 1564;                 // 64-col slices
static constexpr int CPAD   = NSLICE * 64;          // 100096
static constexpr float OOB_COLS = (float)(CPAD - Cn);   // 96 (exp2(0)=1 each)
static constexpr int NT  = Bn / 16;                 // 128 sample tiles
static constexpr int NWV = 4;                       // waves per block
static constexpr int NTW = NT / NWV;                // 32 tiles per wave

#define SCALE_F 30.0f
#define MARGIN_F 0.2f
#define EPS_F 1e-6f
#define L2E_SCALE 43.2808512266689f   /* 30 * log2(e): exp(30*c) = 2^(L2E*c) */

typedef __attribute__((ext_vector_type(8))) short bf16x8;   // 8 bf16 = 4 VGPRs
typedef __attribute__((ext_vector_type(4))) float f32x4;

__device__ __forceinline__ short f2bf_rne(float x) {
    union { float f; unsigned int u; } v; v.f = x;
    unsigned int r = v.u + 0x7fffu + ((v.u >> 16) & 1u);
    return (short)(r >> 16);
}

// ---- kernel 1: fused prep ----
// blocks [0,256)    : pack emb fp32 -> embF (bf16, MFMA B-fragment order),
//                     PRE-SCALED by 30*log2(e) so k_main's exp is a bare v_exp.
//   chunk (t,ks,lane): embF[((t*8+ks)*64+lane)*8 .. +7] = bf16 of
//   L2E * emb[t*16 + (lane&15)][ks*32 + (lane>>4)*8 + j], j=0..7
// blocks [256,768)  : per-sample target cosine -> numv, etv (exact fp32 path)
__global__ __launch_bounds__(256) void k_prep(const float* __restrict__ W,
                                              const float* __restrict__ emb,
                                              const int* __restrict__ tgt,
                                              short* __restrict__ embF,
                                              float* __restrict__ numv,
                                              float* __restrict__ etv) {
    const int blk = blockIdx.x;
    if (blk < 256) {
        const int t     = blk >> 1;
        const int chunk = (blk & 1) * 256 + threadIdx.x;   // [0,512)
        const int ks    = chunk >> 6;
        const int lane  = chunk & 63;
        const int q     = lane >> 4;
        const int cr    = lane & 15;
        const float* src = emb + (size_t)(t * 16 + cr) * Dn + ks * 32 + q * 8;
        float4 x0 = *(const float4*)(src);
        float4 x1 = *(const float4*)(src + 4);
        bf16x8 o;
        o[0] = f2bf_rne(x0.x * L2E_SCALE); o[1] = f2bf_rne(x0.y * L2E_SCALE);
        o[2] = f2bf_rne(x0.z * L2E_SCALE); o[3] = f2bf_rne(x0.w * L2E_SCALE);
        o[4] = f2bf_rne(x1.x * L2E_SCALE); o[5] = f2bf_rne(x1.y * L2E_SCALE);
        o[6] = f2bf_rne(x1.z * L2E_SCALE); o[7] = f2bf_rne(x1.w * L2E_SCALE);
        *(bf16x8*)(embF + (size_t)((t * 8 + ks) * 64 + lane) * 8) = o;
    } else {
        const int b    = (blk - 256) * 4 + (threadIdx.x >> 6);
        const int lane = threadIdx.x & 63;
        const int t    = tgt[b];
        float4 x = *(const float4*)(W + (size_t)t * Dn + lane * 4);
        float4 e = *(const float4*)(emb + b * Dn + lane * 4);
        float dot = x.x * e.x + x.y * e.y + x.z * e.z + x.w * e.w;
        float ss  = x.x * x.x + x.y * x.y + x.z * x.z + x.w * x.w;
#pragma unroll
        for (int o = 1; o < 64; o <<= 1) {
            dot += __shfl_xor(dot, o);
            ss  += __shfl_xor(ss, o);
        }
        if (lane == 0) {
            float cosv = dot / fmaxf(sqrtf(ss), 1e-12f);
            cosv = fminf(fmaxf(cosv, -1.f), 1.f);
            const float num = SCALE_F * cosf(acosf(cosv) + MARGIN_F);
            numv[b] = num;
            etv[b]  = __expf(SCALE_F * cosv);
        }
    }
}

// ---- kernel 2: main fused GEMM + exp row-sum ----
// Block = one 64-col slice, 4 waves. Cooperative W-normalize prologue (1x
// traffic, shared via LDS), then each wave owns 32 sample-tiles, barrier-free.
__global__ __launch_bounds__(256, 2) void k_main(const float* __restrict__ W,
                                                 const short* __restrict__ embF,
                                                 float* __restrict__ partial) {
    __shared__ short afrag_sh[4 * 8 * 64 * 8];   // 32 KB, [(ct*8+ks)*64+lane]*8
    const int tid  = threadIdx.x;
    const int lane = tid & 63;
    const int wv   = tid >> 6;    // wave id 0..3 (= ct in prologue, = sample quarter)
    const int q    = lane >> 4;   // quad 0..3
    const int cr   = lane & 15;
    const int sl   = blockIdx.x;
    const int cbase = sl * 64;

    // ---- prologue: wave wv normalizes cols [cbase+wv*16, +16) ----
    // A layout (16x16x32): lane holds A[m=cr][k=q*8+j] per 32-wide k-step.
    {
        const int c = cbase + wv * 16 + cr;
        const float* wr = W + (size_t)c * Dn;
        float ss = 0.0f;
        if (c < Cn) {
#pragma unroll
            for (int ks = 0; ks < 8; ++ks) {
                float4 x0 = *(const float4*)(wr + ks * 32 + q * 8);
                float4 x1 = *(const float4*)(wr + ks * 32 + q * 8 + 4);
                ss += x0.x * x0.x + x0.y * x0.y + x0.z * x0.z + x0.w * x0.w;
                ss += x1.x * x1.x + x1.y * x1.y + x1.z * x1.z + x1.w * x1.w;
            }
        }
        // lanes {cr, cr+16, cr+32, cr+48} hold 64 distinct elements of row c
        ss += __shfl_xor(ss, 16);
        ss += __shfl_xor(ss, 32);
        const float rn = 1.0f / fmaxf(sqrtf(ss), 1e-12f);
#pragma unroll
        for (int ks = 0; ks < 8; ++ks) {
            bf16x8 a = {0, 0, 0, 0, 0, 0, 0, 0};
            if (c < Cn) {   // pass 2: reload (cache-hot), scale, convert
                float4 x0 = *(const float4*)(wr + ks * 32 + q * 8);
                float4 x1 = *(const float4*)(wr + ks * 32 + q * 8 + 4);
                a[0] = f2bf_rne(x0.x * rn); a[1] = f2bf_rne(x0.y * rn);
                a[2] = f2bf_rne(x0.z * rn); a[3] = f2bf_rne(x0.w * rn);
                a[4] = f2bf_rne(x1.x * rn); a[5] = f2bf_rne(x1.y * rn);
                a[6] = f2bf_rne(x1.z * rn); a[7] = f2bf_rne(x1.w * rn);
            }
            *(bf16x8*)(afrag_sh + (size_t)((wv * 8 + ks) * 64 + lane) * 8) = a;
        }
    }
    __syncthreads();

    float* pout = partial + (size_t)sl * Bn;
    const bf16x8* bsrc = (const bf16x8*)embF;   // chunk-indexed (16B units)
    const int t0 = wv * NTW;                    // this wave's sample quarter

    // B fragments for tile t: chunks t*512 + ks*64 + lane (coalesced 1KB/inst)
    auto load_b = [&](bf16x8* bf, int t) {
        const bf16x8* p = bsrc + (size_t)t * 512 + lane;
#pragma unroll
        for (int ks = 0; ks < 8; ++ks) bf[ks] = p[ks * 64];
    };

    auto compute = [&](const bf16x8* bf, int t) {
        f32x4 a0 = {0.f, 0.f, 0.f, 0.f};
        f32x4 a1 = {0.f, 0.f, 0.f, 0.f};
        f32x4 a2 = {0.f, 0.f, 0.f, 0.f};
        f32x4 a3 = {0.f, 0.f, 0.f, 0.f};
        // T5: favor MFMA-entering waves on the CU scheduler. Barrier-free
        // loop => co-resident waves are in different phases; the priority
        // bump feeds the matrix pipe during other waves' exp/store tails.
        __builtin_amdgcn_s_setprio(1);
#pragma unroll
        for (int ks = 0; ks < 8; ++ks) {
            const short* ap = afrag_sh + (size_t)(ks * 64 + lane) * 8;
            bf16x8 w0 = *(const bf16x8*)(ap);            // ct stride = 4096 shorts
            bf16x8 w1 = *(const bf16x8*)(ap + 4096);
            bf16x8 w2 = *(const bf16x8*)(ap + 8192);
            bf16x8 w3 = *(const bf16x8*)(ap + 12288);
            a0 = __builtin_amdgcn_mfma_f32_16x16x32_bf16(w0, bf[ks], a0, 0, 0, 0);
            a1 = __builtin_amdgcn_mfma_f32_16x16x32_bf16(w1, bf[ks], a1, 0, 0, 0);
            a2 = __builtin_amdgcn_mfma_f32_16x16x32_bf16(w2, bf[ks], a2, 0, 0, 0);
            a3 = __builtin_amdgcn_mfma_f32_16x16x32_bf16(w3, bf[ks], a3, 0, 0, 0);
        }
        __builtin_amdgcn_s_setprio(0);
        // D layout: col=lane&15=sample, row=q*4+reg=class. d = 30*log2e*cos,
        // so exp(30*cos) = exp2(d): one v_exp_f32, no mul. 4 independent
        // partial chains shorten the dependent add tail.
        float s0 = 0.f, s1 = 0.f, s2 = 0.f, s3 = 0.f;
#pragma unroll
        for (int r = 0; r < 4; ++r) {
            s0 += __builtin_amdgcn_exp2f(a0[r]);
            s1 += __builtin_amdgcn_exp2f(a1[r]);
            s2 += __builtin_amdgcn_exp2f(a2[r]);
            s3 += __builtin_amdgcn_exp2f(a3[r]);
        }
        float s = (s0 + s1) + (s2 + s3);
        s += __shfl_xor(s, 16);
        s += __shfl_xor(s, 32);
        if (lane < 16) pout[t * 16 + cr] = s;   // coalesced 64B store
    };

    bf16x8 b0[8], b1[8];
    load_b(b0, t0);
    for (int i = 0; i < NTW; i += 2) {
        load_b(b1, t0 + i + 1);                          // ~1 tile ahead of use
        compute(b0, t0 + i);
        load_b(b0, (i + 2) < NTW ? (t0 + i + 2) : t0);   // overrun-clamped
        compute(b1, t0 + i + 1);
    }
}

// ---- kernel 3: fused rowsum + loss ----
// 32 blocks x 256 thr; block owns 64 samples; tid = qq*64 + l, qq = slice quarter.
__global__ __launch_bounds__(256) void k_finish(const float* __restrict__ partial,
                                                const float* __restrict__ numv,
                                                const float* __restrict__ etv,
                                                float* __restrict__ out) {
    __shared__ float red[64];
    const int l  = threadIdx.x & 63;
    const int qq = threadIdx.x >> 6;
    const int b  = blockIdx.x * 64 + l;

    if (threadIdx.x < 64) red[threadIdx.x] = 0.0f;
    __syncthreads();

    const int s0 = qq * (NSLICE / 4);            // 1564 = 4*391 exact
    const int s1 = s0 + (NSLICE / 4);
    float acc = 0.0f;
    for (int s = s0; s < s1; ++s) acc += partial[(size_t)s * Bn + b];
    atomicAdd(&red[l], acc);
    __syncthreads();

    if (threadIdx.x < 64) {
        const float num  = numv[b];
        const float excl = red[l] - OOB_COLS - etv[b];   // drop padding + target col
        const float denom = __expf(num) + excl;
        float term = num - logf(denom + EPS_F);
#pragma unroll
        for (int o = 1; o < 64; o <<= 1) term += __shfl_xor(term, o);
        if (l == 0) atomicAdd(out, -term / (float)Bn);
    }
}

extern "C" void kernel_launch(void* const* d_in, const int* in_sizes, int n_in,
                              void* d_out, int out_size, void* d_ws, size_t ws_size,
                              hipStream_t stream) {
    const float* emb = (const float*)d_in[0];   // 2048*256
    const float* W   = (const float*)d_in[1];   // 100000*256
    const int*   tgt = (const int*)d_in[2];     // 2048
    float* out = (float*)d_out;

    char* ws = (char*)d_ws;
    short* embF    = (short*)ws;                             // 1 MB (fragment order)
    float* partial = (float*)(ws + (1 << 20));               // 1564*2048*4 = 12.8 MB
    float* numv    = partial + (size_t)NSLICE * Bn;          // 8 KB
    float* etv     = numv + Bn;                              // 8 KB

    hipMemsetAsync(out, 0, sizeof(float), stream);
    k_prep<<<768, 256, 0, stream>>>(W, emb, tgt, embF, numv, etv);
    k_main<<<NSLICE, 256, 0, stream>>>(W, embF, partial);
    k_finish<<<32, 256, 0, stream>>>(partial, numv, etv, out);
}